// Round 20
// baseline (523.418 us; speedup 1.0000x reference)
//
#include <hip/hip_runtime.h>
#include <cstddef>
#include <cstring>

#define T_     8000
#define L_     803
#define C_     256
#define D_     512
#define NB_    32
#define FK_    20
#define NBATCH 4
#define EPS_   1e-5f

#define NVALID 208           // 52 strips x 4 slices (logical blocks)
#define NGRID  224           // physical grid; g>=52 exits early
#define NTHR   512           // 8 waves
#define SG     1040          // LDS group stride bytes: 64 cols * 16B + 16B pad

typedef __attribute__((ext_vector_type(8))) short bf16x8;
typedef __attribute__((ext_vector_type(4))) short shortx4;
typedef __attribute__((ext_vector_type(4))) float f32x4;
typedef unsigned long long u64;

__device__ __forceinline__ short f2bf(float x) {
  unsigned u = __float_as_uint(x);
  u += 0x7FFF + ((u >> 16) & 1);   // RNE
  return (short)(u >> 16);
}
__device__ __forceinline__ float bf2f(short u) {
  return __uint_as_float(((unsigned)(unsigned short)u) << 16);
}

__device__ __forceinline__ void astore8(void* p, u64 v) {
  __hip_atomic_store((u64*)p, v, __ATOMIC_RELAXED, __HIP_MEMORY_SCOPE_AGENT);
}

struct __align__(64) Bar { unsigned cnt; unsigned phase; unsigned pad[14]; };

__device__ __forceinline__ void bar_heavy(Bar* b, unsigned nblk, int tid) {
  __syncthreads();
  if (tid == 0) {
    __threadfence();
    unsigned ph = __hip_atomic_load(&b->phase, __ATOMIC_RELAXED, __HIP_MEMORY_SCOPE_AGENT);
    unsigned prev = __hip_atomic_fetch_add(&b->cnt, 1u, __ATOMIC_RELAXED, __HIP_MEMORY_SCOPE_AGENT);
    if (prev == nblk - 1) {
      __hip_atomic_store(&b->cnt, 0u, __ATOMIC_RELAXED, __HIP_MEMORY_SCOPE_AGENT);
      __hip_atomic_store(&b->phase, ph + 1u, __ATOMIC_RELEASE, __HIP_MEMORY_SCOPE_AGENT);
    } else {
      while (__hip_atomic_load(&b->phase, __ATOMIC_RELAXED, __HIP_MEMORY_SCOPE_AGENT) == ph)
        __builtin_amdgcn_s_sleep(2);
    }
    __threadfence();
  }
  __syncthreads();
}

struct KParams {
  const float *x, *w_enc, *w1, *wd, *w2, *w_dec;
  const float *g1, *bb1, *m1, *v1;
  const float *g2, *bb2, *m2, *v2;
  const float *g3, *bb3, *m3, *v3;
  float *out;
  float *s1, *o1, *s2, *o2, *s3, *o3;
  float *yb;                  // y [n][l][c] f32
  short *w1b, *w2b;           // bf16 weights
  unsigned short *zh;         // z halo: [32][52 strip][4 y][64 col][128 d] bf16
  unsigned short *b3g;        // b3:     [16][52 strip][64 col][512 d] bf16
  unsigned short *b1b;        // BN1(h): [32][n][l][c] bf16
  unsigned *ct;               // per-logical-block monotone counter [208]
  Bar *gbar;
};

// ---------- full-grid prep: BN fold + weight bf16 conversion ----------
__global__ __launch_bounds__(256) void prep_kernel(KParams p) {
  const int gtid = blockIdx.x * 256 + threadIdx.x;
  const int stride = gridDim.x * 256;
  for (int i = gtid; i < NB_ * C_; i += stride) {
    float s = p.g1[i] * rsqrtf(p.v1[i] + EPS_);
    p.s1[i] = s; p.o1[i] = p.bb1[i] - p.m1[i] * s;
  }
  for (int i = gtid; i < NB_ * D_; i += stride) {
    float s2 = p.g2[i] * rsqrtf(p.v2[i] + EPS_);
    p.s2[i] = s2; p.o2[i] = p.bb2[i] - p.m2[i] * s2;
    float s3 = p.g3[i] * rsqrtf(p.v3[i] + EPS_);
    p.s3[i] = s3; p.o3[i] = p.bb3[i] - p.m3[i] * s3;
  }
  for (int i = gtid; i < NB_ * D_ * C_ / 4; i += stride) {
    float4 a = ((const float4*)p.w1)[i];
    float4 b = ((const float4*)p.w2)[i];
    shortx4 sa, sb;
    sa[0] = f2bf(a.x); sa[1] = f2bf(a.y); sa[2] = f2bf(a.z); sa[3] = f2bf(a.w);
    sb[0] = f2bf(b.x); sb[1] = f2bf(b.y); sb[2] = f2bf(b.z); sb[3] = f2bf(b.w);
    *(shortx4*)&p.w1b[4 * i] = sa;
    *(shortx4*)&p.w2b[4 * i] = sb;
  }
}

__global__ __launch_bounds__(NTHR) void tasnet_fused(KParams p) {
  const int tid = threadIdx.x;
  const int bid = blockIdx.x;

  // XCD swizzle: siblings (same strip, y=0..3) share bid%8 -> same XCD L2.
  const int r8 = bid & 7, t8 = bid >> 3;
  const int g = (t8 >> 2) * 8 + r8;           // strip-group 0..55
  const int y = t8 & 3;                       // slice
  if (g >= 52) return;
  const int vid = g * 4 + y;                  // logical block id
  const int xt = g % 13, n = g / 13;
  const int l0 = xt * 64;

  const int lane = tid & 63, wv = tid >> 6;   // 8 waves
  const int frow = lane & 15, kg = lane >> 4;
  const int cw = wv & 3;
  const int ch = wv >> 2;
  const int cbase = y * 64 + cw * 16 + kg * 4;

  __shared__ __align__(16) char BsRaw[64 * SG];   // 66.5 KB [kgrp 0..63][col][16B]
  __shared__ __align__(16) char ZsOwn[16 * SG];   // 16.6 KB own z slice

  const size_t B1B = (size_t)NBATCH * L_ * C_;
  const size_t ZHB = (size_t)52 * 4 * 64 * 128;
  const size_t B3B = (size_t)52 * 64 * 512;

  // ---------------- encoder -> hreg ; publish b1[0] ----------------
  f32x4 hreg[2], xer[2];
  {
    const float* xn_ = p.x + (size_t)n * T_;
#pragma unroll
    for (int jb = 0; jb < 2; ++jb) {
      int gl = l0 + ch * 32 + jb * 16 + frow;
      int t0 = gl * 10 - 20;
      float xw[FK_];
#pragma unroll
      for (int k = 0; k < FK_; ++k) {
        int t = t0 + k;
        xw[k] = (t >= 0 && t < T_) ? xn_[t] : 0.f;
      }
#pragma unroll
      for (int jj = 0; jj < 4; ++jj) {
        const float* w = p.w_enc + (cbase + jj) * FK_;
        float acc = 0.f;
#pragma unroll
        for (int k = 0; k < FK_; ++k) acc = fmaf(xw[k], w[k], acc);
        hreg[jb][jj] = acc;
        xer[jb][jj] = acc;
      }
    }
    unsigned short* b0 = p.b1b + (size_t)n * (L_ * C_);
    float4 s1v = *(const float4*)(p.s1 + cbase);
    float4 o1v = *(const float4*)(p.o1 + cbase);
#pragma unroll
    for (int jb = 0; jb < 2; ++jb) {
      int gl = l0 + ch * 32 + jb * 16 + frow;
      if (gl < L_) {
        shortx4 pk;
        pk[0] = f2bf(fmaf(hreg[jb][0], s1v.x, o1v.x));
        pk[1] = f2bf(fmaf(hreg[jb][1], s1v.y, o1v.y));
        pk[2] = f2bf(fmaf(hreg[jb][2], s1v.z, o1v.z));
        pk[3] = f2bf(fmaf(hreg[jb][3], s1v.w, o1v.w));
        *(shortx4*)(b0 + (size_t)gl * C_ + cbase) = pk;
      }
    }
  }
  __syncthreads();
  if (tid == 0)
    __hip_atomic_store(&p.ct[vid], 1u, __ATOMIC_RELAXED, __HIP_MEMORY_SCOPE_AGENT);

  // ---------------- 32 residual blocks ----------------
  for (int layer = 0; layer < NB_; ++layer) {
    const int dil = 1 << (layer & 7);
    const int step = (dil <= 64) ? 1 : 2;
    const int w = (dil < 64) ? dil : 64;
    const float* s1p = p.s1 + layer * C_;
    const float* o1p = p.o1 + layer * C_;
    const float* s2p = p.s2 + layer * D_;
    const float* o2p = p.o2 + layer * D_;
    const float* s3p = p.s3 + layer * D_;
    const float* o3p = p.o3 + layer * D_;
    const unsigned short* b1_cur = p.b1b + (size_t)layer * B1B + (size_t)n * (L_ * C_);
    unsigned short* b1_nxt = p.b1b + (size_t)(layer + 1) * B1B + (size_t)n * (L_ * C_);
    unsigned short* zh_my = p.zh + (size_t)layer * ZHB
                            + ((size_t)(n * 13 + xt) * 4 + y) * (64 * 128);
    unsigned short* b3s = p.b3g + (size_t)(layer & 15) * B3B
                          + (size_t)(n * 13 + xt) * (64 * 512);

    // ===== issue W1 fragment loads early (hidden under B1/S1/sibling copy) =====
    bf16x8 w1f[8];
    {
      const short* W1 = p.w1b + (size_t)layer * D_ * C_
                        + (size_t)(y * 128 + wv * 16 + frow) * C_;
#pragma unroll
      for (int k0 = 0; k0 < 8; ++k0)
        w1f[k0] = *(const bf16x8*)(W1 + k0 * 32 + kg * 8);
    }

    // ===== B1 own slice -> Bs =====
    {
      float4 s1v = *(const float4*)(s1p + cbase);
      float4 o1v = *(const float4*)(o1p + cbase);
#pragma unroll
      for (int jb = 0; jb < 2; ++jb) {
        int col = ch * 32 + jb * 16 + frow;
        shortx4 pk;
        pk[0] = f2bf(fmaf(hreg[jb][0], s1v.x, o1v.x));
        pk[1] = f2bf(fmaf(hreg[jb][1], s1v.y, o1v.y));
        pk[2] = f2bf(fmaf(hreg[jb][2], s1v.z, o1v.z));
        pk[3] = f2bf(fmaf(hreg[jb][3], s1v.w, o1v.w));
        *(shortx4*)(BsRaw + (cbase >> 3) * SG + col * 16 + (kg & 1) * 8) = pk;
      }
    }
    // S1: siblings' b1(layer) published
    if (wv == 0 && lane < 3) {
      int idx = g * 4 + ((y + 1 + lane) & 3);
      unsigned tgt = (unsigned)(3 * layer + 1);
      while (__hip_atomic_load(&p.ct[idx], __ATOMIC_RELAXED, __HIP_MEMORY_SCOPE_AGENT) < tgt)
        __builtin_amdgcn_s_sleep(1);
    }
    __syncthreads();
    // sibling b1 slices -> Bs (cached)
    {
      int col = tid >> 3, k8 = tid & 7;
      int gl = l0 + col;
      bool lv = gl < L_;
#pragma unroll
      for (int s = 1; s < 4; ++s) {
        int sc = ((y + s) & 3) * 64 + k8 * 8;
        bf16x8 pk = {0, 0, 0, 0, 0, 0, 0, 0};
        if (lv) pk = *(const bf16x8*)(b1_cur + (size_t)gl * C_ + sc);
        *(bf16x8*)(BsRaw + (sc >> 3) * SG + col * 16) = pk;
      }
    }
    __syncthreads();

    // ===== stage1 MFMA: register A-operand =====
    f32x4 acc1[4] = {};
#pragma unroll
    for (int k0 = 0; k0 < 8; ++k0) {
#pragma unroll
      for (int jb = 0; jb < 4; ++jb) {
        bf16x8 bfr = *(bf16x8*)(BsRaw + (k0 * 4 + kg) * SG + (jb * 16 + frow) * 16);
        acc1[jb] = __builtin_amdgcn_mfma_f32_16x16x32_bf16(w1f[k0], bfr, acc1[jb], 0, 0, 0);
      }
    }

    // ===== issue W2 fragment loads (hidden under z-publish/S2/B3) =====
    // w2f[i] holds fragment for global k0 = (y*4 + i) & 15  (own chunk first)
    bf16x8 w2f[16];
    {
      const short* W2 = p.w2b + (size_t)layer * C_ * D_
                        + (size_t)(y * 64 + cw * 16 + frow) * D_;
#pragma unroll
      for (int i = 0; i < 16; ++i) {
        int k0 = (y * 4 + i) & 15;
        w2f[i] = *(const bf16x8*)(W2 + k0 * 32 + kg * 8);
      }
    }

    // ===== z = BN2(acc1) -> ZsOwn + zh halo publish (sc1, cross-XCD) =====
    {
      const bool hasL = (xt - step) >= 0;
      const bool hasR = (xt + step) <= 12;
      int dbr = wv * 16 + kg * 4;
      float4 s2v = *(const float4*)(s2p + y * 128 + dbr);
      float4 o2v = *(const float4*)(o2p + y * 128 + dbr);
#pragma unroll
      for (int jb = 0; jb < 4; ++jb) {
        int col = jb * 16 + frow;
        shortx4 pk;
        pk[0] = f2bf(fmaf(acc1[jb][0], s2v.x, o2v.x));
        pk[1] = f2bf(fmaf(acc1[jb][1], s2v.y, o2v.y));
        pk[2] = f2bf(fmaf(acc1[jb][2], s2v.z, o2v.z));
        pk[3] = f2bf(fmaf(acc1[jb][3], s2v.w, o2v.w));
        *(shortx4*)(ZsOwn + (dbr >> 3) * SG + col * 16 + (kg & 1) * 8) = pk;
        bool haloL = hasL && (col < w);
        bool haloR = hasR && (col >= 64 - w);
        if (haloL || haloR) {
          u64 u;
          __builtin_memcpy(&u, &pk, 8);
          astore8(zh_my + (size_t)col * 128 + dbr, u);
        }
      }
    }
    __syncthreads();
    if (tid == 0)
      __hip_atomic_store(&p.ct[vid], (unsigned)(3 * layer + 2),
                         __ATOMIC_RELAXED, __HIP_MEMORY_SCOPE_AGENT);

    // ===== B3 own d-slice (two-pass: interior, then edges after S2) =====
    {
      const int col = tid >> 3;
      const int op = tid & 7;
      const int gcol = l0 + col;
      const int gl2 = gcol - dil, gr2 = gcol + dil;
      const bool remL = (gl2 >= 0) && (gl2 < l0);
      const bool remR = (gr2 < L_) && (gr2 >= l0 + 64);
      const bool isRem = remL || remR;
      const unsigned short* zhl = p.zh + (size_t)layer * ZHB;
#pragma unroll
      for (int pass = 0; pass < 2; ++pass) {
        if (pass == 1) {
          if (wv == 0 && lane < 2) {
            int xn2 = xt + ((lane == 0) ? -step : step);
            if (xn2 >= 0 && xn2 <= 12) {
              int idx = (n * 13 + xn2) * 4 + y;
              unsigned tgt = (unsigned)(3 * layer + 2);
              while (__hip_atomic_load(&p.ct[idx], __ATOMIC_RELAXED, __HIP_MEMORY_SCOPE_AGENT) < tgt)
                __builtin_amdgcn_s_sleep(1);
            }
          }
          __syncthreads();
        }
        if ((pass == 0) == isRem) continue;
#pragma unroll
        for (int oc = 0; oc < 2; ++oc) {
          int drel = op * 16 + oc * 8;
          int dglob = y * 128 + drel;
          const float* wdp = p.wd + (size_t)layer * D_ * 3 + dglob * 3;
          float4 wq[6];
#pragma unroll
          for (int q = 0; q < 6; ++q) wq[q] = *(const float4*)(wdp + 4 * q);
          float4 s3a = *(const float4*)(s3p + dglob), s3b = *(const float4*)(s3p + dglob + 4);
          float4 o3a = *(const float4*)(o3p + dglob), o3b = *(const float4*)(o3p + dglob + 4);
          bf16x8 zc = *(bf16x8*)(ZsOwn + (drel >> 3) * SG + col * 16);
          bf16x8 zl = {0, 0, 0, 0, 0, 0, 0, 0};
          bf16x8 zr = {0, 0, 0, 0, 0, 0, 0, 0};
          if (gl2 >= 0) {
            if (!remL) zl = *(bf16x8*)(ZsOwn + (drel >> 3) * SG + (gl2 - l0) * 16);
            else zl = *(const bf16x8*)(zhl + ((size_t)(n * 13 + (gl2 >> 6)) * 4 + y) * (64 * 128)
                                       + (size_t)(gl2 & 63) * 128 + drel);
          }
          if (gr2 < L_) {
            if (!remR) zr = *(bf16x8*)(ZsOwn + (drel >> 3) * SG + (gr2 - l0) * 16);
            else zr = *(const bf16x8*)(zhl + ((size_t)(n * 13 + (gr2 >> 6)) * 4 + y) * (64 * 128)
                                       + (size_t)(gr2 & 63) * 128 + drel);
          }
          bf16x8 pb;
#pragma unroll
          for (int j = 0; j < 8; ++j) {
            float w0v = wq[(3 * j + 0) >> 2][(3 * j + 0) & 3];
            float w1v = wq[(3 * j + 1) >> 2][(3 * j + 1) & 3];
            float w2v = wq[(3 * j + 2) >> 2][(3 * j + 2) & 3];
            float m = bf2f(zc[j]) * w1v;
            m = fmaf(bf2f(zl[j]), w0v, m);
            m = fmaf(bf2f(zr[j]), w2v, m);
            float s3v = (j < 4) ? s3a[j] : s3b[j - 4];
            float o3v = (j < 4) ? o3a[j] : o3b[j - 4];
            pb[j] = f2bf(fmaf(m, s3v, o3v));
          }
          *(bf16x8*)(BsRaw + (y * 16 + (drel >> 3)) * SG + col * 16) = pb;
          *(bf16x8*)(b3s + (size_t)col * 512 + dglob) = pb;   // same-XCD siblings
        }
      }
    }
    __syncthreads();   // own b3 in Bs; b3g stores drained
    if (tid == 0)
      __hip_atomic_store(&p.ct[vid], (unsigned)(3 * layer + 3),
                         __ATOMIC_RELAXED, __HIP_MEMORY_SCOPE_AGENT);

    // ===== stage2 partA: own-y K-chunk (before S3 rendezvous) =====
    f32x4 acc2[2] = {};
#pragma unroll
    for (int i = 0; i < 4; ++i) {
      int k0 = (y * 4 + i) & 15;
#pragma unroll
      for (int jb = 0; jb < 2; ++jb) {
        int col = ch * 32 + jb * 16 + frow;
        bf16x8 bfr = *(bf16x8*)(BsRaw + (k0 * 4 + kg) * SG + col * 16);
        acc2[jb] = __builtin_amdgcn_mfma_f32_16x16x32_bf16(w2f[i], bfr, acc2[jb], 0, 0, 0);
      }
    }
    // S3: siblings' b3 published
    if (wv == 0 && lane < 3) {
      int idx = g * 4 + ((y + 1 + lane) & 3);
      unsigned tgt = (unsigned)(3 * layer + 3);
      while (__hip_atomic_load(&p.ct[idx], __ATOMIC_RELAXED, __HIP_MEMORY_SCOPE_AGENT) < tgt)
        __builtin_amdgcn_s_sleep(1);
    }
    __syncthreads();
    // sibling b3 -> Bs (cached)
    {
      int col = tid >> 3, k8 = tid & 7;
#pragma unroll
      for (int s = 1; s < 4; ++s) {
        int y2 = (y + s) & 3;
        const unsigned short* src = b3s + (size_t)col * 512 + y2 * 128 + k8 * 16;
        bf16x8 v0 = *(const bf16x8*)(src);
        bf16x8 v1 = *(const bf16x8*)(src + 8);
        *(bf16x8*)(BsRaw + (y2 * 16 + k8 * 2) * SG + col * 16) = v0;
        *(bf16x8*)(BsRaw + (y2 * 16 + k8 * 2 + 1) * SG + col * 16) = v1;
      }
    }
    __syncthreads();

    // ===== stage2 partB: remaining 12 K-chunks ; hreg += =====
#pragma unroll
    for (int i = 4; i < 16; ++i) {
      int k0 = (y * 4 + i) & 15;
#pragma unroll
      for (int jb = 0; jb < 2; ++jb) {
        int col = ch * 32 + jb * 16 + frow;
        bf16x8 bfr = *(bf16x8*)(BsRaw + (k0 * 4 + kg) * SG + col * 16);
        acc2[jb] = __builtin_amdgcn_mfma_f32_16x16x32_bf16(w2f[i], bfr, acc2[jb], 0, 0, 0);
      }
    }
#pragma unroll
    for (int jb = 0; jb < 2; ++jb)
#pragma unroll
      for (int jj = 0; jj < 4; ++jj)
        hreg[jb][jj] += acc2[jb][jj];

    // publish b1[layer+1] = BN1_{l+1}(h')
    if (layer + 1 < NB_) {
      float4 s1v = *(const float4*)(p.s1 + (layer + 1) * C_ + cbase);
      float4 o1v = *(const float4*)(p.o1 + (layer + 1) * C_ + cbase);
#pragma unroll
      for (int jb = 0; jb < 2; ++jb) {
        int gl = l0 + ch * 32 + jb * 16 + frow;
        if (gl < L_) {
          shortx4 pk;
          pk[0] = f2bf(fmaf(hreg[jb][0], s1v.x, o1v.x));
          pk[1] = f2bf(fmaf(hreg[jb][1], s1v.y, o1v.y));
          pk[2] = f2bf(fmaf(hreg[jb][2], s1v.z, o1v.z));
          pk[3] = f2bf(fmaf(hreg[jb][3], s1v.w, o1v.w));
          *(shortx4*)(b1_nxt + (size_t)gl * C_ + cbase) = pk;
        }
      }
    }
    __syncthreads();
    if (tid == 0)
      __hip_atomic_store(&p.ct[vid], (unsigned)(3 * layer + 4),
                         __ATOMIC_RELAXED, __HIP_MEMORY_SCOPE_AGENT);
  }

  // ---------------- mask: y = xe * sigmoid(h) -> yb ----------------
  {
    float* yn = p.yb + (size_t)n * ((size_t)L_ * C_);
#pragma unroll
    for (int jb = 0; jb < 2; ++jb) {
      int gl = l0 + ch * 32 + jb * 16 + frow;
      if (gl < L_) {
        float4 v;
        v.x = xer[jb][0] / (1.f + expf(-hreg[jb][0]));
        v.y = xer[jb][1] / (1.f + expf(-hreg[jb][1]));
        v.z = xer[jb][2] / (1.f + expf(-hreg[jb][2]));
        v.w = xer[jb][3] / (1.f + expf(-hreg[jb][3]));
        *(float4*)(yn + (size_t)gl * C_ + cbase) = v;
      }
    }
  }
  bar_heavy(p.gbar, NVALID, tid);

  // ---------------- decoder ----------------
  for (int idx = vid * NTHR + tid; idx < NBATCH * T_; idx += NVALID * NTHR) {
    int t = idx % T_;
    int nn = idx / T_;
    int tt = t + FK_;
    int lq = tt / 10;      // in [2, 801]
    int k0 = tt % 10;
    const float* y0 = p.yb + (size_t)nn * ((size_t)L_ * C_) + (size_t)lq * C_;
    const float* y1 = y0 - C_;
    float acc = 0.f;
#pragma unroll 8
    for (int c = 0; c < C_; c++) {
      const float* wr2 = p.w_dec + c * FK_;
      acc = fmaf(y0[c], wr2[k0], acc);
      acc = fmaf(y1[c], wr2[k0 + 10], acc);
    }
    p.out[idx] = acc;
  }
}

extern "C" void kernel_launch(void* const* d_in, const int* in_sizes, int n_in,
                              void* d_out, int out_size, void* d_ws, size_t ws_size,
                              hipStream_t stream) {
  KParams hp;
  hp.x     = (const float*)d_in[0];
  hp.w_enc = (const float*)d_in[1];
  hp.w1    = (const float*)d_in[2];
  hp.wd    = (const float*)d_in[3];
  hp.w2    = (const float*)d_in[4];
  hp.w_dec = (const float*)d_in[5];
  hp.g1 = (const float*)d_in[6];  hp.bb1 = (const float*)d_in[7];
  hp.m1 = (const float*)d_in[8];  hp.v1  = (const float*)d_in[9];
  hp.g2 = (const float*)d_in[10]; hp.bb2 = (const float*)d_in[11];
  hp.m2 = (const float*)d_in[12]; hp.v2  = (const float*)d_in[13];
  hp.g3 = (const float*)d_in[14]; hp.bb3 = (const float*)d_in[15];
  hp.m3 = (const float*)d_in[16]; hp.v3  = (const float*)d_in[17];
  hp.out = (float*)d_out;

  char* cur = (char*)d_ws;
  auto take = [&](size_t bytes) { char* r = cur; cur += (bytes + 255) & ~(size_t)255; return r; };
  hp.gbar = (Bar*)take(256);
  hp.ct   = (unsigned*)take(NVALID * 4);
  hp.s1 = (float*)take(NB_ * C_ * 4);
  hp.o1 = (float*)take(NB_ * C_ * 4);
  hp.s2 = (float*)take(NB_ * D_ * 4);
  hp.o2 = (float*)take(NB_ * D_ * 4);
  hp.s3 = (float*)take(NB_ * D_ * 4);
  hp.o3 = (float*)take(NB_ * D_ * 4);
  hp.yb  = (float*)take((size_t)NBATCH * L_ * C_ * 4);
  hp.w1b = (short*)take((size_t)NB_ * D_ * C_ * 2);
  hp.w2b = (short*)take((size_t)NB_ * D_ * C_ * 2);
  hp.b1b = (unsigned short*)take((size_t)NB_ * NBATCH * L_ * C_ * 2);     // 32 bufs
  hp.b3g = (unsigned short*)take((size_t)16 * 52 * 64 * 512 * 2);         // 16 bufs
  hp.zh  = (unsigned short*)take((size_t)NB_ * 52 * 4 * 64 * 128 * 2);    // 32 bufs

  hipMemsetAsync(d_ws, 0, 2048, stream);   // gbar + ct
  prep_kernel<<<dim3(1024), dim3(256), 0, stream>>>(hp);
  tasnet_fused<<<dim3(NGRID), dim3(NTHR), 0, stream>>>(hp);
}

// Round 22
// 509.537 us; speedup vs baseline: 1.0272x; 1.0272x over previous
//
#include <hip/hip_runtime.h>
#include <cstddef>
#include <cstring>

#define T_     8000
#define L_     803
#define C_     256
#define D_     512
#define NB_    32
#define FK_    20
#define NBATCH 4
#define EPS_   1e-5f

#define NVALID 208           // 52 strips x 4 slices (logical blocks)
#define NGRID  224           // physical grid; g>=52 exits early
#define NTHR   512           // 8 waves
#define SG     1040          // LDS group stride bytes: 64 cols * 16B + 16B pad

typedef __attribute__((ext_vector_type(8))) short bf16x8;
typedef __attribute__((ext_vector_type(4))) short shortx4;
typedef __attribute__((ext_vector_type(4))) float f32x4;
typedef unsigned long long u64;

__device__ __forceinline__ short f2bf(float x) {
  unsigned u = __float_as_uint(x);
  u += 0x7FFF + ((u >> 16) & 1);   // RNE
  return (short)(u >> 16);
}
__device__ __forceinline__ float bf2f(short u) {
  return __uint_as_float(((unsigned)(unsigned short)u) << 16);
}

__device__ __forceinline__ void astore8(void* p, u64 v) {
  __hip_atomic_store((u64*)p, v, __ATOMIC_RELAXED, __HIP_MEMORY_SCOPE_AGENT);
}

struct __align__(64) Bar { unsigned cnt; unsigned phase; unsigned pad[14]; };

__device__ __forceinline__ void bar_heavy(Bar* b, unsigned nblk, int tid) {
  __syncthreads();
  if (tid == 0) {
    __threadfence();
    unsigned ph = __hip_atomic_load(&b->phase, __ATOMIC_RELAXED, __HIP_MEMORY_SCOPE_AGENT);
    unsigned prev = __hip_atomic_fetch_add(&b->cnt, 1u, __ATOMIC_RELAXED, __HIP_MEMORY_SCOPE_AGENT);
    if (prev == nblk - 1) {
      __hip_atomic_store(&b->cnt, 0u, __ATOMIC_RELAXED, __HIP_MEMORY_SCOPE_AGENT);
      __hip_atomic_store(&b->phase, ph + 1u, __ATOMIC_RELEASE, __HIP_MEMORY_SCOPE_AGENT);
    } else {
      while (__hip_atomic_load(&b->phase, __ATOMIC_RELAXED, __HIP_MEMORY_SCOPE_AGENT) == ph)
        __builtin_amdgcn_s_sleep(2);
    }
    __threadfence();
  }
  __syncthreads();
}

struct KParams {
  const float *x, *w_enc, *w1, *wd, *w2, *w_dec;
  const float *g1, *bb1, *m1, *v1;
  const float *g2, *bb2, *m2, *v2;
  const float *g3, *bb3, *m3, *v3;
  float *out;
  float *s1, *o1, *s2, *o2, *s3, *o3;
  float *yb;                  // y [n][l][c] f32
  short *w1b, *w2b;           // bf16 weights
  unsigned short *zh;         // z halo: [32][52 strip][4 y][64 col][128 d] bf16
  unsigned short *b3g;        // b3:     [16][52 strip][64 col][512 d] bf16
  unsigned short *b1b;        // BN1(h): [32][n][l][c] bf16
  unsigned *ct;               // per-logical-block monotone counter [208] (sc1)
  Bar *gbar;
};

// ---------- full-grid prep: BN fold + weight bf16 conversion ----------
__global__ __launch_bounds__(256) void prep_kernel(KParams p) {
  const int gtid = blockIdx.x * 256 + threadIdx.x;
  const int stride = gridDim.x * 256;
  for (int i = gtid; i < NB_ * C_; i += stride) {
    float s = p.g1[i] * rsqrtf(p.v1[i] + EPS_);
    p.s1[i] = s; p.o1[i] = p.bb1[i] - p.m1[i] * s;
  }
  for (int i = gtid; i < NB_ * D_; i += stride) {
    float s2 = p.g2[i] * rsqrtf(p.v2[i] + EPS_);
    p.s2[i] = s2; p.o2[i] = p.bb2[i] - p.m2[i] * s2;
    float s3 = p.g3[i] * rsqrtf(p.v3[i] + EPS_);
    p.s3[i] = s3; p.o3[i] = p.bb3[i] - p.m3[i] * s3;
  }
  for (int i = gtid; i < NB_ * D_ * C_ / 4; i += stride) {
    float4 a = ((const float4*)p.w1)[i];
    float4 b = ((const float4*)p.w2)[i];
    shortx4 sa, sb;
    sa[0] = f2bf(a.x); sa[1] = f2bf(a.y); sa[2] = f2bf(a.z); sa[3] = f2bf(a.w);
    sb[0] = f2bf(b.x); sb[1] = f2bf(b.y); sb[2] = f2bf(b.z); sb[3] = f2bf(b.w);
    *(shortx4*)&p.w1b[4 * i] = sa;
    *(shortx4*)&p.w2b[4 * i] = sb;
  }
}

__global__ __launch_bounds__(NTHR) void tasnet_fused(KParams p) {
  const int tid = threadIdx.x;
  const int bid = blockIdx.x;

  // XCD swizzle: siblings (same strip, y=0..3) share bid%8 (L2-locality heuristic).
  const int r8 = bid & 7, t8 = bid >> 3;
  const int g = (t8 >> 2) * 8 + r8;           // strip-group 0..55
  const int y = t8 & 3;                       // slice
  if (g >= 52) return;
  const int vid = g * 4 + y;                  // logical block id
  const int xt = g % 13, n = g / 13;
  const int l0 = xt * 64;

  const int lane = tid & 63, wv = tid >> 6;   // 8 waves
  const int frow = lane & 15, kg = lane >> 4;
  const int cw = wv & 3;
  const int ch = wv >> 2;
  const int cbase = y * 64 + cw * 16 + kg * 4;

  __shared__ __align__(16) char BsRaw[64 * SG];   // 66.5 KB [kgrp 0..63][col][16B]
  __shared__ __align__(16) char ZsOwn[16 * SG];   // 16.6 KB own z slice

  const size_t B1B = (size_t)NBATCH * L_ * C_;
  const size_t ZHB = (size_t)52 * 4 * 64 * 128;
  const size_t B3B = (size_t)52 * 64 * 512;

  // ---------------- encoder -> hreg ; publish b1[0] ----------------
  f32x4 hreg[2], xer[2];
  {
    const float* xn_ = p.x + (size_t)n * T_;
#pragma unroll
    for (int jb = 0; jb < 2; ++jb) {
      int gl = l0 + ch * 32 + jb * 16 + frow;
      int t0 = gl * 10 - 20;
      float xw[FK_];
#pragma unroll
      for (int k = 0; k < FK_; ++k) {
        int t = t0 + k;
        xw[k] = (t >= 0 && t < T_) ? xn_[t] : 0.f;
      }
#pragma unroll
      for (int jj = 0; jj < 4; ++jj) {
        const float* w = p.w_enc + (cbase + jj) * FK_;
        float acc = 0.f;
#pragma unroll
        for (int k = 0; k < FK_; ++k) acc = fmaf(xw[k], w[k], acc);
        hreg[jb][jj] = acc;
        xer[jb][jj] = acc;
      }
    }
    unsigned short* b0 = p.b1b + (size_t)n * (L_ * C_);
    float4 s1v = *(const float4*)(p.s1 + cbase);
    float4 o1v = *(const float4*)(p.o1 + cbase);
#pragma unroll
    for (int jb = 0; jb < 2; ++jb) {
      int gl = l0 + ch * 32 + jb * 16 + frow;
      if (gl < L_) {
        shortx4 pk;
        pk[0] = f2bf(fmaf(hreg[jb][0], s1v.x, o1v.x));
        pk[1] = f2bf(fmaf(hreg[jb][1], s1v.y, o1v.y));
        pk[2] = f2bf(fmaf(hreg[jb][2], s1v.z, o1v.z));
        pk[3] = f2bf(fmaf(hreg[jb][3], s1v.w, o1v.w));
        *(shortx4*)(b0 + (size_t)gl * C_ + cbase) = pk;
      }
    }
  }
  __syncthreads();
  if (tid == 0)
    __hip_atomic_store(&p.ct[vid], 1u, __ATOMIC_RELAXED, __HIP_MEMORY_SCOPE_AGENT);

  // ---------------- 32 residual blocks ----------------
  for (int layer = 0; layer < NB_; ++layer) {
    const int dil = 1 << (layer & 7);
    const int step = (dil <= 64) ? 1 : 2;
    const int w = (dil < 64) ? dil : 64;
    const float* s1p = p.s1 + layer * C_;
    const float* o1p = p.o1 + layer * C_;
    const float* s2p = p.s2 + layer * D_;
    const float* o2p = p.o2 + layer * D_;
    const float* s3p = p.s3 + layer * D_;
    const float* o3p = p.o3 + layer * D_;
    const unsigned short* b1_cur = p.b1b + (size_t)layer * B1B + (size_t)n * (L_ * C_);
    unsigned short* b1_nxt = p.b1b + (size_t)(layer + 1) * B1B + (size_t)n * (L_ * C_);
    unsigned short* zh_my = p.zh + (size_t)layer * ZHB
                            + ((size_t)(n * 13 + xt) * 4 + y) * (64 * 128);
    unsigned short* b3s = p.b3g + (size_t)(layer & 15) * B3B
                          + (size_t)(n * 13 + xt) * (64 * 512);

    // ===== B1 own slice -> Bs =====
    {
      float4 s1v = *(const float4*)(s1p + cbase);
      float4 o1v = *(const float4*)(o1p + cbase);
#pragma unroll
      for (int jb = 0; jb < 2; ++jb) {
        int col = ch * 32 + jb * 16 + frow;
        shortx4 pk;
        pk[0] = f2bf(fmaf(hreg[jb][0], s1v.x, o1v.x));
        pk[1] = f2bf(fmaf(hreg[jb][1], s1v.y, o1v.y));
        pk[2] = f2bf(fmaf(hreg[jb][2], s1v.z, o1v.z));
        pk[3] = f2bf(fmaf(hreg[jb][3], s1v.w, o1v.w));
        *(shortx4*)(BsRaw + (cbase >> 3) * SG + col * 16 + (kg & 1) * 8) = pk;
      }
    }
    // S1: siblings' b1(layer) published (sc1 flags — proven protocol)
    if (wv == 0 && lane < 3) {
      int idx = g * 4 + ((y + 1 + lane) & 3);
      unsigned tgt = (unsigned)(3 * layer + 1);
      while (__hip_atomic_load(&p.ct[idx], __ATOMIC_RELAXED, __HIP_MEMORY_SCOPE_AGENT) < tgt)
        __builtin_amdgcn_s_sleep(1);
    }
    __syncthreads();
    // sibling b1 slices -> Bs (cached)
    {
      int col = tid >> 3, k8 = tid & 7;
      int gl = l0 + col;
      bool lv = gl < L_;
#pragma unroll
      for (int s = 1; s < 4; ++s) {
        int sc = ((y + s) & 3) * 64 + k8 * 8;
        bf16x8 pk = {0, 0, 0, 0, 0, 0, 0, 0};
        if (lv) pk = *(const bf16x8*)(b1_cur + (size_t)gl * C_ + sc);
        *(bf16x8*)(BsRaw + (sc >> 3) * SG + col * 16) = pk;
      }
    }
    __syncthreads();

    // ===== stage1 MFMA: d-slice [y*128,+128) x 64 cols, K=256 =====
    f32x4 acc1[4] = {};
    {
      const short* W1 = p.w1b + (size_t)layer * D_ * C_ + (size_t)(y * 128 + wv * 16 + frow) * C_;
#pragma unroll
      for (int k0 = 0; k0 < 8; ++k0) {
        int kb = k0 * 32 + kg * 8;
        bf16x8 af = *(const bf16x8*)(W1 + kb);
#pragma unroll
        for (int jb = 0; jb < 4; ++jb) {
          bf16x8 bfr = *(bf16x8*)(BsRaw + (k0 * 4 + kg) * SG + (jb * 16 + frow) * 16);
          acc1[jb] = __builtin_amdgcn_mfma_f32_16x16x32_bf16(af, bfr, acc1[jb], 0, 0, 0);
        }
      }
    }
    // ===== z = BN2(acc1) -> ZsOwn + zh halo publish (sc1, cross-XCD) =====
    {
      const bool hasL = (xt - step) >= 0;
      const bool hasR = (xt + step) <= 12;
      int dbr = wv * 16 + kg * 4;
      float4 s2v = *(const float4*)(s2p + y * 128 + dbr);
      float4 o2v = *(const float4*)(o2p + y * 128 + dbr);
#pragma unroll
      for (int jb = 0; jb < 4; ++jb) {
        int col = jb * 16 + frow;
        shortx4 pk;
        pk[0] = f2bf(fmaf(acc1[jb][0], s2v.x, o2v.x));
        pk[1] = f2bf(fmaf(acc1[jb][1], s2v.y, o2v.y));
        pk[2] = f2bf(fmaf(acc1[jb][2], s2v.z, o2v.z));
        pk[3] = f2bf(fmaf(acc1[jb][3], s2v.w, o2v.w));
        *(shortx4*)(ZsOwn + (dbr >> 3) * SG + col * 16 + (kg & 1) * 8) = pk;
        bool haloL = hasL && (col < w);
        bool haloR = hasR && (col >= 64 - w);
        if (haloL || haloR) {
          u64 u;
          __builtin_memcpy(&u, &pk, 8);
          astore8(zh_my + (size_t)col * 128 + dbr, u);
        }
      }
    }
    __syncthreads();
    if (tid == 0)
      __hip_atomic_store(&p.ct[vid], (unsigned)(3 * layer + 2),
                         __ATOMIC_RELAXED, __HIP_MEMORY_SCOPE_AGENT);

    // ===== B3 own d-slice (two-pass: interior, then edges after S2) =====
    {
      const int col = tid >> 3;
      const int op = tid & 7;
      const int gcol = l0 + col;
      const int gl2 = gcol - dil, gr2 = gcol + dil;
      const bool remL = (gl2 >= 0) && (gl2 < l0);
      const bool remR = (gr2 < L_) && (gr2 >= l0 + 64);
      const bool isRem = remL || remR;
      const unsigned short* zhl = p.zh + (size_t)layer * ZHB;
#pragma unroll
      for (int pass = 0; pass < 2; ++pass) {
        if (pass == 1) {
          if (wv == 0 && lane < 2) {
            int xn2 = xt + ((lane == 0) ? -step : step);
            if (xn2 >= 0 && xn2 <= 12) {
              int idx = (n * 13 + xn2) * 4 + y;
              unsigned tgt = (unsigned)(3 * layer + 2);
              while (__hip_atomic_load(&p.ct[idx], __ATOMIC_RELAXED, __HIP_MEMORY_SCOPE_AGENT) < tgt)
                __builtin_amdgcn_s_sleep(1);
            }
          }
          __syncthreads();
        }
        if ((pass == 0) == isRem) continue;
#pragma unroll
        for (int oc = 0; oc < 2; ++oc) {
          int drel = op * 16 + oc * 8;
          int dglob = y * 128 + drel;
          const float* wdp = p.wd + (size_t)layer * D_ * 3 + dglob * 3;
          float4 wq[6];
#pragma unroll
          for (int q = 0; q < 6; ++q) wq[q] = *(const float4*)(wdp + 4 * q);
          float4 s3a = *(const float4*)(s3p + dglob), s3b = *(const float4*)(s3p + dglob + 4);
          float4 o3a = *(const float4*)(o3p + dglob), o3b = *(const float4*)(o3p + dglob + 4);
          bf16x8 zc = *(bf16x8*)(ZsOwn + (drel >> 3) * SG + col * 16);
          bf16x8 zl = {0, 0, 0, 0, 0, 0, 0, 0};
          bf16x8 zr = {0, 0, 0, 0, 0, 0, 0, 0};
          if (gl2 >= 0) {
            if (!remL) zl = *(bf16x8*)(ZsOwn + (drel >> 3) * SG + (gl2 - l0) * 16);
            else zl = *(const bf16x8*)(zhl + ((size_t)(n * 13 + (gl2 >> 6)) * 4 + y) * (64 * 128)
                                       + (size_t)(gl2 & 63) * 128 + drel);
          }
          if (gr2 < L_) {
            if (!remR) zr = *(bf16x8*)(ZsOwn + (drel >> 3) * SG + (gr2 - l0) * 16);
            else zr = *(const bf16x8*)(zhl + ((size_t)(n * 13 + (gr2 >> 6)) * 4 + y) * (64 * 128)
                                       + (size_t)(gr2 & 63) * 128 + drel);
          }
          bf16x8 pb;
#pragma unroll
          for (int j = 0; j < 8; ++j) {
            float w0v = wq[(3 * j + 0) >> 2][(3 * j + 0) & 3];
            float w1v = wq[(3 * j + 1) >> 2][(3 * j + 1) & 3];
            float w2v = wq[(3 * j + 2) >> 2][(3 * j + 2) & 3];
            float m = bf2f(zc[j]) * w1v;
            m = fmaf(bf2f(zl[j]), w0v, m);
            m = fmaf(bf2f(zr[j]), w2v, m);
            float s3v = (j < 4) ? s3a[j] : s3b[j - 4];
            float o3v = (j < 4) ? o3a[j] : o3b[j - 4];
            pb[j] = f2bf(fmaf(m, s3v, o3v));
          }
          *(bf16x8*)(BsRaw + (y * 16 + (drel >> 3)) * SG + col * 16) = pb;
          *(bf16x8*)(b3s + (size_t)col * 512 + dglob) = pb;
        }
      }
    }
    __syncthreads();   // own b3 in Bs; b3g stores drained
    if (tid == 0)
      __hip_atomic_store(&p.ct[vid], (unsigned)(3 * layer + 3),
                         __ATOMIC_RELAXED, __HIP_MEMORY_SCOPE_AGENT);

    // ===== stage2 partA: own-y K-chunk (overlaps S3 sibling lag) =====
    f32x4 acc2[2] = {};
    {
      const short* W2 = p.w2b + (size_t)layer * C_ * D_ + (size_t)(y * 64 + cw * 16 + frow) * D_;
#pragma unroll
      for (int i = 0; i < 4; ++i) {
        int k0 = y * 4 + i;
        int kb = k0 * 32 + kg * 8;
        bf16x8 af = *(const bf16x8*)(W2 + kb);
#pragma unroll
        for (int jb = 0; jb < 2; ++jb) {
          int col = ch * 32 + jb * 16 + frow;
          bf16x8 bfr = *(bf16x8*)(BsRaw + (k0 * 4 + kg) * SG + col * 16);
          acc2[jb] = __builtin_amdgcn_mfma_f32_16x16x32_bf16(af, bfr, acc2[jb], 0, 0, 0);
        }
      }
    }
    // S3: siblings' b3 published
    if (wv == 0 && lane < 3) {
      int idx = g * 4 + ((y + 1 + lane) & 3);
      unsigned tgt = (unsigned)(3 * layer + 3);
      while (__hip_atomic_load(&p.ct[idx], __ATOMIC_RELAXED, __HIP_MEMORY_SCOPE_AGENT) < tgt)
        __builtin_amdgcn_s_sleep(1);
    }
    __syncthreads();
    // sibling b3 -> Bs (cached)
    {
      int col = tid >> 3, k8 = tid & 7;
#pragma unroll
      for (int s = 1; s < 4; ++s) {
        int y2 = (y + s) & 3;
        const unsigned short* src = b3s + (size_t)col * 512 + y2 * 128 + k8 * 16;
        bf16x8 v0 = *(const bf16x8*)(src);
        bf16x8 v1 = *(const bf16x8*)(src + 8);
        *(bf16x8*)(BsRaw + (y2 * 16 + k8 * 2) * SG + col * 16) = v0;
        *(bf16x8*)(BsRaw + (y2 * 16 + k8 * 2 + 1) * SG + col * 16) = v1;
      }
    }
    __syncthreads();

    // ===== stage2 partB: remaining 12 K-chunks ; hreg += =====
    {
      const short* W2 = p.w2b + (size_t)layer * C_ * D_ + (size_t)(y * 64 + cw * 16 + frow) * D_;
#pragma unroll
      for (int i = 1; i < 4; ++i) {
#pragma unroll
        for (int q = 0; q < 4; ++q) {
          int k0 = ((y + i) & 3) * 4 + q;
          int kb = k0 * 32 + kg * 8;
          bf16x8 af = *(const bf16x8*)(W2 + kb);
#pragma unroll
          for (int jb = 0; jb < 2; ++jb) {
            int col = ch * 32 + jb * 16 + frow;
            bf16x8 bfr = *(bf16x8*)(BsRaw + (k0 * 4 + kg) * SG + col * 16);
            acc2[jb] = __builtin_amdgcn_mfma_f32_16x16x32_bf16(af, bfr, acc2[jb], 0, 0, 0);
          }
        }
      }
    }
#pragma unroll
    for (int jb = 0; jb < 2; ++jb)
#pragma unroll
      for (int jj = 0; jj < 4; ++jj)
        hreg[jb][jj] += acc2[jb][jj];

    // publish b1[layer+1] = BN1_{l+1}(h')
    if (layer + 1 < NB_) {
      float4 s1v = *(const float4*)(p.s1 + (layer + 1) * C_ + cbase);
      float4 o1v = *(const float4*)(p.o1 + (layer + 1) * C_ + cbase);
#pragma unroll
      for (int jb = 0; jb < 2; ++jb) {
        int gl = l0 + ch * 32 + jb * 16 + frow;
        if (gl < L_) {
          shortx4 pk;
          pk[0] = f2bf(fmaf(hreg[jb][0], s1v.x, o1v.x));
          pk[1] = f2bf(fmaf(hreg[jb][1], s1v.y, o1v.y));
          pk[2] = f2bf(fmaf(hreg[jb][2], s1v.z, o1v.z));
          pk[3] = f2bf(fmaf(hreg[jb][3], s1v.w, o1v.w));
          *(shortx4*)(b1_nxt + (size_t)gl * C_ + cbase) = pk;
        }
      }
    }
    __syncthreads();
    if (tid == 0)
      __hip_atomic_store(&p.ct[vid], (unsigned)(3 * layer + 4),
                         __ATOMIC_RELAXED, __HIP_MEMORY_SCOPE_AGENT);
  }

  // ---------------- mask: y = xe * sigmoid(h) -> yb ----------------
  {
    float* yn = p.yb + (size_t)n * ((size_t)L_ * C_);
#pragma unroll
    for (int jb = 0; jb < 2; ++jb) {
      int gl = l0 + ch * 32 + jb * 16 + frow;
      if (gl < L_) {
        float4 v;
        v.x = xer[jb][0] / (1.f + expf(-hreg[jb][0]));
        v.y = xer[jb][1] / (1.f + expf(-hreg[jb][1]));
        v.z = xer[jb][2] / (1.f + expf(-hreg[jb][2]));
        v.w = xer[jb][3] / (1.f + expf(-hreg[jb][3]));
        *(float4*)(yn + (size_t)gl * C_ + cbase) = v;
      }
    }
  }
  bar_heavy(p.gbar, NVALID, tid);

  // ---------------- decoder ----------------
  for (int idx = vid * NTHR + tid; idx < NBATCH * T_; idx += NVALID * NTHR) {
    int t = idx % T_;
    int nn = idx / T_;
    int tt = t + FK_;
    int lq = tt / 10;      // in [2, 801]
    int k0 = tt % 10;
    const float* y0 = p.yb + (size_t)nn * ((size_t)L_ * C_) + (size_t)lq * C_;
    const float* y1 = y0 - C_;
    float acc = 0.f;
#pragma unroll 8
    for (int c = 0; c < C_; c++) {
      const float* wr2 = p.w_dec + c * FK_;
      acc = fmaf(y0[c], wr2[k0], acc);
      acc = fmaf(y1[c], wr2[k0 + 10], acc);
    }
    p.out[idx] = acc;
  }
}

extern "C" void kernel_launch(void* const* d_in, const int* in_sizes, int n_in,
                              void* d_out, int out_size, void* d_ws, size_t ws_size,
                              hipStream_t stream) {
  KParams hp;
  hp.x     = (const float*)d_in[0];
  hp.w_enc = (const float*)d_in[1];
  hp.w1    = (const float*)d_in[2];
  hp.wd    = (const float*)d_in[3];
  hp.w2    = (const float*)d_in[4];
  hp.w_dec = (const float*)d_in[5];
  hp.g1 = (const float*)d_in[6];  hp.bb1 = (const float*)d_in[7];
  hp.m1 = (const float*)d_in[8];  hp.v1  = (const float*)d_in[9];
  hp.g2 = (const float*)d_in[10]; hp.bb2 = (const float*)d_in[11];
  hp.m2 = (const float*)d_in[12]; hp.v2  = (const float*)d_in[13];
  hp.g3 = (const float*)d_in[14]; hp.bb3 = (const float*)d_in[15];
  hp.m3 = (const float*)d_in[16]; hp.v3  = (const float*)d_in[17];
  hp.out = (float*)d_out;

  char* cur = (char*)d_ws;
  auto take = [&](size_t bytes) { char* r = cur; cur += (bytes + 255) & ~(size_t)255; return r; };
  hp.gbar = (Bar*)take(256);
  hp.ct   = (unsigned*)take(NVALID * 4);
  hp.s1 = (float*)take(NB_ * C_ * 4);
  hp.o1 = (float*)take(NB_ * C_ * 4);
  hp.s2 = (float*)take(NB_ * D_ * 4);
  hp.o2 = (float*)take(NB_ * D_ * 4);
  hp.s3 = (float*)take(NB_ * D_ * 4);
  hp.o3 = (float*)take(NB_ * D_ * 4);
  hp.yb  = (float*)take((size_t)NBATCH * L_ * C_ * 4);
  hp.w1b = (short*)take((size_t)NB_ * D_ * C_ * 2);
  hp.w2b = (short*)take((size_t)NB_ * D_ * C_ * 2);
  hp.b1b = (unsigned short*)take((size_t)NB_ * NBATCH * L_ * C_ * 2);     // 32 bufs
  hp.b3g = (unsigned short*)take((size_t)16 * 52 * 64 * 512 * 2);         // 16 bufs
  hp.zh  = (unsigned short*)take((size_t)NB_ * 52 * 4 * 64 * 128 * 2);    // 32 bufs

  hipMemsetAsync(d_ws, 0, 2048, stream);   // gbar + ct
  prep_kernel<<<dim3(1024), dim3(256), 0, stream>>>(hp);
  tasnet_fused<<<dim3(NGRID), dim3(NTHR), 0, stream>>>(hp);
}